// Round 1
// baseline (1777.334 us; speedup 1.0000x reference)
//
#include <hip/hip_runtime.h>
#include <stdint.h>
#include <stddef.h>

// ESTHead: B=4 S=2048 HID=4096 H=32 D=128
// Pipeline:
//   rope_table (interleaved cos/sin float2 LUT)  +  f2b(X, Wk, Wv) -> bf16
//   gemm_rope_fused: k = rope(X@Wk^T), v = rope(X@Wv^T) in ONE launch
//     [bf16 MFMA 16x16x32, 128x128 tile, BK=64, global_load_lds 16B, XOR-swizzled LDS]
//   scores = eq . k (uint-vectorized) ; softmax ; attn_out = p . v (4-seg pipelined)
//   fp32 skinny tail (float4 loads): Wo -> LN -> (W0,W1,SiLU) -> W2 -> LN -> Ws + bs
//
// R1 lesson: sincosf in the GEMM epilogue = libm call -> acc spills. RoPE trig from LUT.
// R2: fuse KV GEMMs (1 launch), float2 LUT, vectorize scores/softmax_av/skinny loads
//     (G13: hipcc never auto-vectorizes bf16/scalar streams; 2-2.5x per-kernel cost).

#define BB 4
#define SS 2048
#define HIDDIM 4096
#define NH 32
#define HD 128
#define MROWS (BB * SS)  // 8192

typedef __attribute__((ext_vector_type(8))) __bf16 bf16x8;
typedef __attribute__((ext_vector_type(4))) float f32x4;

static __device__ __forceinline__ unsigned short f2bf(float f) {
  union { float f; unsigned u; } c; c.f = f;
  unsigned u = c.u;
  u += 0x7fffu + ((u >> 16) & 1u);
  return (unsigned short)(u >> 16);
}
static __device__ __forceinline__ float bf2f(unsigned short h) {
  union { unsigned u; float f; } c; c.u = ((unsigned)h) << 16;
  return c.f;
}

// LUT: (cos, sin) of s * 10000^(-ip/64), s in [0,2048), ip in [0,64), interleaved float2
__global__ __launch_bounds__(256) void rope_table_kernel(float2* __restrict__ cssn) {
  int idx = blockIdx.x * 256 + threadIdx.x;
  int s = idx >> 6, ip = idx & 63;
  float theta = exp2f(-0.2076205059304601f * (float)ip);  // log2(10000)/64
  float ph = (float)s * theta;
  float2 v; v.x = cosf(ph); v.y = sinf(ph);
  cssn[idx] = v;
}

__global__ __launch_bounds__(256) void f2b_kernel(const float4* __restrict__ in,
                                                  ushort4* __restrict__ out, int n4) {
  int stride = gridDim.x * blockDim.x;
  for (int i = blockIdx.x * blockDim.x + threadIdx.x; i < n4; i += stride) {
    float4 v = in[i];
    ushort4 o;
    o.x = f2bf(v.x); o.y = f2bf(v.y); o.z = f2bf(v.z); o.w = f2bf(v.w);
    out[i] = o;
  }
}

static __device__ __forceinline__ void load16_lds(const void* g, void* l) {
  __builtin_amdgcn_global_load_lds(
      (const __attribute__((address_space(1))) unsigned int*)g,
      (__attribute__((address_space(3))) unsigned int*)l, 16, 0, 0);
}

// C = rope(A @ W^T) in bf16 for BOTH Wk and Wv in one launch.
// blockIdx.x in [0,64): <32 -> K projection head bn, >=32 -> V projection head bn-32.
// Block: 256 thr = 4 waves (2x2), 128x128 tile, BK=64, single LDS buffer, 2 barriers/iter.
// LDS chunk XOR-swizzle: slot jj of row holds global chunk (jj ^ (row&7)) so the
// ds_read_b128 fragment reads hit <=2-way bank conflicts (free) despite no padding.
__global__ __launch_bounds__(256) void gemm_rope_kernel(
    const unsigned short* __restrict__ A,
    const unsigned short* __restrict__ Wk,
    const unsigned short* __restrict__ Wv,
    const float2* __restrict__ rope_cs,
    unsigned short* __restrict__ Ck,
    unsigned short* __restrict__ Cv) {
  __shared__ __align__(16) unsigned char smem[32768];
  unsigned char* sA = smem;
  unsigned char* sB = smem + 16384;

  const int tid  = threadIdx.x;
  const int wave = tid >> 6;
  const int lane = tid & 63;
  const int wm = wave >> 1, wn = wave & 1;
  const int quad = lane >> 4, l15 = lane & 15;
  const int bm = blockIdx.y;
  const int bnx = blockIdx.x;           // 0..63
  const int bn = bnx & 31;              // head index within the selected projection
  const unsigned short* W = (bnx < 32) ? Wk : Wv;
  unsigned short* C = (bnx < 32) ? Ck : Cv;

  f32x4 acc[4][4];
#pragma unroll
  for (int i = 0; i < 4; ++i)
#pragma unroll
    for (int j = 0; j < 4; ++j)
      acc[i][j] = (f32x4){0.f, 0.f, 0.f, 0.f};

  const int crow = lane >> 3;      // row within 8-row staging chunk
  const int jj   = lane & 7;       // LDS 16B slot within row
  const int scol = jj ^ crow;      // swizzled global chunk to fetch
  const unsigned short* Abase = A + (size_t)(bm * 128) * HIDDIM;
  const unsigned short* Wbase = W + (size_t)(bn * 128) * HIDDIM;

  for (int kt = 0; kt < HIDDIM; kt += 64) {
#pragma unroll
    for (int it = 0; it < 4; ++it) {
      int rt = wave * 32 + it * 8 + crow;          // tile row 0..127
      int lo = (wave * 4 + it) * 1024;             // wave-uniform LDS chunk base
      load16_lds(Abase + (size_t)rt * HIDDIM + kt + scol * 8, sA + lo);
      load16_lds(Wbase + (size_t)rt * HIDDIM + kt + scol * 8, sB + lo);
    }
    __syncthreads();  // vmcnt(0) drain + barrier: LDS tiles ready
#pragma unroll
    for (int ks = 0; ks < 2; ++ks) {
      const int ch = ((ks * 4 + quad) ^ (l15 & 7)) * 16;
      bf16x8 af[4], bfr[4];
#pragma unroll
      for (int i = 0; i < 4; ++i) {
        int arow = wm * 64 + i * 16 + l15;
        af[i] = *(const bf16x8*)(sA + arow * 128 + ch);
      }
#pragma unroll
      for (int j = 0; j < 4; ++j) {
        int brow = wn * 64 + j * 16 + l15;
        bfr[j] = *(const bf16x8*)(sB + brow * 128 + ch);
      }
#pragma unroll
      for (int i = 0; i < 4; ++i)
#pragma unroll
        for (int j = 0; j < 4; ++j)
          acc[i][j] = __builtin_amdgcn_mfma_f32_16x16x32_bf16(af[i], bfr[j], acc[i][j], 0, 0, 0);
    }
    __syncthreads();  // all waves done reading before next overwrite
  }

  // Epilogue: RoPE (float2 LUT) + packed bf16x2 store. C/D layout: col = lane&15, row = quad*4+reg.
  // N-tile (128) == head dim, so d = col_local; RoPE pair (2i,2i+1) = adjacent lanes.
  const int colb = bn * 128;
#pragma unroll
  for (int j = 0; j < 4; ++j) {
    const int col_local = wn * 64 + j * 16 + l15;  // == d in [0,128)
    const int ip  = col_local >> 1;
    const int odd = col_local & 1;
#pragma unroll
    for (int i = 0; i < 4; ++i) {
#pragma unroll
      for (int r = 0; r < 4; ++r) {
        int token = bm * 128 + wm * 64 + i * 16 + quad * 4 + r;
        int spos  = token & (SS - 1);
        float2 cs2 = rope_cs[spos * 64 + ip];
        float val = acc[i][j][r];
        float oth = __shfl_xor(val, 1);
        float o = odd ? (val * cs2.x + oth * cs2.y) : (val * cs2.x - oth * cs2.y);
        float o_pair = __shfl_xor(o, 1);  // even lane grabs odd lane's result
        if (!odd) {
          unsigned int packed = (unsigned int)f2bf(o) | ((unsigned int)f2bf(o_pair) << 16);
          *(unsigned int*)(C + (size_t)token * HIDDIM + colb + col_local) = packed;
        }
      }
    }
  }
}

// scores[b,h,s] = sum_d eq[h,d] * k[b,s,h,d]; one wave per (b,h,s). uint-vectorized bf16 pair.
__global__ __launch_bounds__(256) void scores_kernel(const unsigned short* __restrict__ kb,
                                                     const float* __restrict__ eq,
                                                     float* __restrict__ scores) {
  int gw   = blockIdx.x * 4 + (threadIdx.x >> 6);  // (b*32+h)*2048 + s
  int lane = threadIdx.x & 63;
  int s = gw & (SS - 1);
  int h = (gw >> 11) & (NH - 1);
  int b = gw >> 16;
  const unsigned short* kp = kb + (size_t)(b * SS + s) * HIDDIM + h * HD + lane * 2;
  unsigned kv = *(const unsigned*)kp;
  float2 q2 = *(const float2*)(eq + h * HD + lane * 2);
  float p = bf2f((unsigned short)(kv & 0xffffu)) * q2.x +
            bf2f((unsigned short)(kv >> 16)) * q2.y;
#pragma unroll
  for (int off = 32; off > 0; off >>= 1) p += __shfl_down(p, off);
  if (lane == 0) scores[gw] = p;
}

// One block per (b,h): softmax over S then attn_out[d] = sum_s p_s * v[b,s,h,d]
// Phase 3: 4 s-segments x 64 d-pairs; uint loads (2 bf16), LDS combine across segments.
__global__ __launch_bounds__(256) void softmax_av_kernel(const float* __restrict__ scores,
                                                         const unsigned short* __restrict__ vb,
                                                         float* __restrict__ attn_out) {
  __shared__ float p[SS];
  __shared__ float red[8];
  __shared__ float acc2[3][HD];
  const int bh = blockIdx.x, b = bh >> 5, h = bh & 31;
  const int tid = threadIdx.x, lane = tid & 63, wave = tid >> 6;
  const float* sc = scores + (size_t)bh * SS;

  float m = -1e30f;
  for (int i = tid; i < SS; i += 256) m = fmaxf(m, sc[i]);
#pragma unroll
  for (int off = 32; off > 0; off >>= 1) m = fmaxf(m, __shfl_down(m, off));
  if (lane == 0) red[wave] = m;
  __syncthreads();
  if (tid == 0) red[4] = fmaxf(fmaxf(red[0], red[1]), fmaxf(red[2], red[3]));
  __syncthreads();
  const float M = red[4];

  float lsum = 0.f;
  for (int i = tid; i < SS; i += 256) { float e = expf(sc[i] - M); p[i] = e; lsum += e; }
#pragma unroll
  for (int off = 32; off > 0; off >>= 1) lsum += __shfl_down(lsum, off);
  __syncthreads();
  if (lane == 0) red[wave] = lsum;
  __syncthreads();
  const float Ssum = red[0] + red[1] + red[2] + red[3];

  const int dp  = (tid & 63) * 2;   // d pair base: 0,2,...,126
  const int seg = tid >> 6;         // s segment 0..3 (512 each)
  const unsigned short* vp = vb + (size_t)(b * SS + seg * 512) * HIDDIM + h * HD + dp;
  float a0 = 0.f, a1 = 0.f;
#pragma unroll 4
  for (int s = 0; s < 512; ++s) {
    unsigned v2 = *(const unsigned*)(vp + (size_t)s * HIDDIM);
    float w = p[seg * 512 + s];
    a0 += w * bf2f((unsigned short)(v2 & 0xffffu));
    a1 += w * bf2f((unsigned short)(v2 >> 16));
  }
  if (seg) { acc2[seg - 1][dp] = a0; acc2[seg - 1][dp + 1] = a1; }
  __syncthreads();
  if (seg == 0) {
    a0 += acc2[0][dp] + acc2[1][dp] + acc2[2][dp];
    a1 += acc2[0][dp + 1] + acc2[1][dp + 1] + acc2[2][dp + 1];
    float inv = 1.f / Ssum;
    attn_out[(size_t)b * HIDDIM + h * HD + dp]     = a0 * inv;
    attn_out[(size_t)b * HIDDIM + h * HD + dp + 1] = a1 * inv;
  }
}

// y[b,n] = sum_k x[b,k]*W[n,k] (+bias). x: 4xK fp32. One wave per n. float4 loads.
__global__ __launch_bounds__(256) void skinny_kernel(const float* __restrict__ W,
                                                     const float* __restrict__ x,
                                                     float* __restrict__ y,
                                                     int N, int K,
                                                     const float* __restrict__ bias) {
  int n = blockIdx.x * 4 + (threadIdx.x >> 6);
  int lane = threadIdx.x & 63;
  const float4* w4 = (const float4*)(W + (size_t)n * K);
  const float4* x0 = (const float4*)x;
  const float4* x1 = (const float4*)(x + K);
  const float4* x2 = (const float4*)(x + 2 * K);
  const float4* x3 = (const float4*)(x + 3 * K);
  const int K4 = K >> 2;
  float a0 = 0.f, a1 = 0.f, a2 = 0.f, a3 = 0.f;
#pragma unroll 4
  for (int k = lane; k < K4; k += 64) {
    float4 wv = w4[k];
    float4 v0 = x0[k], v1 = x1[k], v2 = x2[k], v3 = x3[k];
    a0 += wv.x * v0.x + wv.y * v0.y + wv.z * v0.z + wv.w * v0.w;
    a1 += wv.x * v1.x + wv.y * v1.y + wv.z * v1.z + wv.w * v1.w;
    a2 += wv.x * v2.x + wv.y * v2.y + wv.z * v2.z + wv.w * v2.w;
    a3 += wv.x * v3.x + wv.y * v3.y + wv.z * v3.z + wv.w * v3.w;
  }
#pragma unroll
  for (int off = 32; off > 0; off >>= 1) {
    a0 += __shfl_down(a0, off); a1 += __shfl_down(a1, off);
    a2 += __shfl_down(a2, off); a3 += __shfl_down(a3, off);
  }
  if (lane == 0) {
    float bv = bias ? bias[n] : 0.f;
    y[n] = a0 + bv; y[N + n] = a1 + bv; y[2 * N + n] = a2 + bv; y[3 * N + n] = a3 + bv;
  }
}

// c[b,n] = (x@W0^T) * silu(x@W1^T), fused, float4 loads
__global__ __launch_bounds__(256) void skinny_glu_kernel(const float* __restrict__ W0,
                                                         const float* __restrict__ W1,
                                                         const float* __restrict__ x,
                                                         float* __restrict__ c,
                                                         int N, int K) {
  int n = blockIdx.x * 4 + (threadIdx.x >> 6);
  int lane = threadIdx.x & 63;
  const float4* w0 = (const float4*)(W0 + (size_t)n * K);
  const float4* w1 = (const float4*)(W1 + (size_t)n * K);
  const float4* x0 = (const float4*)x;
  const float4* x1 = (const float4*)(x + K);
  const float4* x2 = (const float4*)(x + 2 * K);
  const float4* x3 = (const float4*)(x + 3 * K);
  const int K4 = K >> 2;
  float a0 = 0.f, a1 = 0.f, a2 = 0.f, a3 = 0.f;
  float g0 = 0.f, g1 = 0.f, g2 = 0.f, g3 = 0.f;
#pragma unroll 2
  for (int k = lane; k < K4; k += 64) {
    float4 wa = w0[k], wg = w1[k];
    float4 v0 = x0[k], v1 = x1[k], v2 = x2[k], v3 = x3[k];
    a0 += wa.x * v0.x + wa.y * v0.y + wa.z * v0.z + wa.w * v0.w;
    a1 += wa.x * v1.x + wa.y * v1.y + wa.z * v1.z + wa.w * v1.w;
    a2 += wa.x * v2.x + wa.y * v2.y + wa.z * v2.z + wa.w * v2.w;
    a3 += wa.x * v3.x + wa.y * v3.y + wa.z * v3.z + wa.w * v3.w;
    g0 += wg.x * v0.x + wg.y * v0.y + wg.z * v0.z + wg.w * v0.w;
    g1 += wg.x * v1.x + wg.y * v1.y + wg.z * v1.z + wg.w * v1.w;
    g2 += wg.x * v2.x + wg.y * v2.y + wg.z * v2.z + wg.w * v2.w;
    g3 += wg.x * v3.x + wg.y * v3.y + wg.z * v3.z + wg.w * v3.w;
  }
#pragma unroll
  for (int off = 32; off > 0; off >>= 1) {
    a0 += __shfl_down(a0, off); a1 += __shfl_down(a1, off);
    a2 += __shfl_down(a2, off); a3 += __shfl_down(a3, off);
    g0 += __shfl_down(g0, off); g1 += __shfl_down(g1, off);
    g2 += __shfl_down(g2, off); g3 += __shfl_down(g3, off);
  }
  if (lane == 0) {
    c[n]         = a0 * (g0 / (1.f + expf(-g0)));
    c[N + n]     = a1 * (g1 / (1.f + expf(-g1)));
    c[2 * N + n] = a2 * (g2 / (1.f + expf(-g2)));
    c[3 * N + n] = a3 * (g3 / (1.f + expf(-g3)));
  }
}

__global__ __launch_bounds__(256) void ln_kernel(const float* __restrict__ x,
                                                 const float* __restrict__ g,
                                                 const float* __restrict__ bta,
                                                 float* __restrict__ y) {
  __shared__ float rs[8], rs2[8];
  const int b = blockIdx.x, tid = threadIdx.x, lane = tid & 63, wave = tid >> 6;
  const float* xr = x + (size_t)b * HIDDIM;
  float s = 0.f, s2 = 0.f;
  for (int i = tid; i < HIDDIM; i += 256) { float v = xr[i]; s += v; s2 += v * v; }
#pragma unroll
  for (int off = 32; off > 0; off >>= 1) { s += __shfl_down(s, off); s2 += __shfl_down(s2, off); }
  if (lane == 0) { rs[wave] = s; rs2[wave] = s2; }
  __syncthreads();
  if (tid == 0) { rs[4] = rs[0] + rs[1] + rs[2] + rs[3]; rs2[4] = rs2[0] + rs2[1] + rs2[2] + rs2[3]; }
  __syncthreads();
  const float mu = rs[4] * (1.f / HIDDIM);
  const float var = rs2[4] * (1.f / HIDDIM) - mu * mu;
  const float rstd = rsqrtf(var + 1e-5f);
  float* yr = y + (size_t)b * HIDDIM;
  for (int i = tid; i < HIDDIM; i += 256) yr[i] = (xr[i] - mu) * rstd * g[i] + bta[i];
}

extern "C" void kernel_launch(void* const* d_in, const int* in_sizes, int n_in,
                              void* d_out, int out_size, void* d_ws, size_t ws_size,
                              hipStream_t stream) {
  const float* hidden = (const float*)d_in[0];
  const float* eq     = (const float*)d_in[1];
  const float* Wk     = (const float*)d_in[2];
  const float* Wv     = (const float*)d_in[3];
  const float* Wo     = (const float*)d_in[4];
  const float* W0     = (const float*)d_in[5];
  const float* W1     = (const float*)d_in[6];
  const float* W2     = (const float*)d_in[7];
  const float* Ws     = (const float*)d_in[8];
  const float* bs     = (const float*)d_in[9];
  const float* ln_g   = (const float*)d_in[10];
  const float* ln_b   = (const float*)d_in[11];
  float* out = (float*)d_out;

  char* ws = (char*)d_ws;
  unsigned short* Xb   = (unsigned short*)(ws);               // 8192x4096 bf16 = 64 MiB
  unsigned short* Wkb  = (unsigned short*)(ws + 67108864);    // 32 MiB
  unsigned short* Wvb  = (unsigned short*)(ws + 100663296);   // 32 MiB
  unsigned short* kb   = (unsigned short*)(ws + 134217728);   // 64 MiB (roped k, bf16)
  unsigned short* vb   = (unsigned short*)(ws + 201326592);   // 64 MiB (roped v, bf16)
  float* scores  = (float*)(ws + 268435456);                  // 4*32*2048 fp32 = 1 MiB
  float* attn    = (float*)(ws + 269484032);                  // 4x4096
  float* y1      = (float*)(ws + 269549568);
  float* x1      = (float*)(ws + 269615104);
  float* cbuf    = (float*)(ws + 269680640);                  // 4x12288
  float* y2      = (float*)(ws + 269877248);
  float* x2      = (float*)(ws + 269942784);
  float2* ropeCS = (float2*)(ws + 270008320);                 // 2048*64 float2 = 1 MiB
  (void)in_sizes; (void)n_in; (void)out_size; (void)ws_size;

  rope_table_kernel<<<512, 256, 0, stream>>>(ropeCS);
  f2b_kernel<<<8192, 256, 0, stream>>>((const float4*)hidden, (ushort4*)Xb, (MROWS * HIDDIM) / 4);
  f2b_kernel<<<4096, 256, 0, stream>>>((const float4*)Wk, (ushort4*)Wkb, (4096 * HIDDIM) / 4);
  f2b_kernel<<<4096, 256, 0, stream>>>((const float4*)Wv, (ushort4*)Wvb, (4096 * HIDDIM) / 4);

  dim3 gg(64, 64);  // bnx (K heads 0..31, V heads 32..63) x bm
  gemm_rope_kernel<<<gg, 256, 0, stream>>>(Xb, Wkb, Wvb, ropeCS, kb, vb);

  scores_kernel<<<(BB * NH * SS) / 4, 256, 0, stream>>>(kb, eq, scores);
  softmax_av_kernel<<<BB * NH, 256, 0, stream>>>(scores, vb, attn);

  skinny_kernel<<<4096 / 4, 256, 0, stream>>>(Wo, attn, y1, 4096, 4096, nullptr);
  ln_kernel<<<BB, 256, 0, stream>>>(y1, ln_g, ln_b, x1);
  skinny_glu_kernel<<<12288 / 4, 256, 0, stream>>>(W0, W1, x1, cbuf, 12288, 4096);
  skinny_kernel<<<4096 / 4, 256, 0, stream>>>(W2, cbuf, y2, 4096, 12288, nullptr);
  ln_kernel<<<BB, 256, 0, stream>>>(y2, ln_g, ln_b, x2);
  skinny_kernel<<<2048 / 4, 256, 0, stream>>>(Ws, x2, out, 2048, 4096, bs);
}